// Round 6
// baseline (568.857 us; speedup 1.0000x reference)
//
#include <hip/hip_runtime.h>

// SelfAttention: B=4, T=4096, D=4096, H=128. fp32 in/out, bf16 MFMA compute.
// R9: flash reverted to R6 (best: KVBLK=64, split-2, 2 blk/CU). qkv pushed to
// 4 blocks/CU (16 waves/CU): BM=64, BN=96 (4 n-slices), 40 KB LDS, grid 1024,
// R6 counted-vmcnt loop (B=3 stage ops, bottom vmcnt(4)). tr/merge unchanged.

typedef __bf16 bf16_t;
typedef bf16_t bf16x8 __attribute__((ext_vector_type(8)));
typedef float f32x4 __attribute__((ext_vector_type(4)));
typedef float f32x8 __attribute__((ext_vector_type(8)));

#define MFMA16(A, B, C) __builtin_amdgcn_mfma_f32_16x16x32_bf16((A), (B), (C), 0, 0, 0)

__device__ __forceinline__ void async_cp16(const bf16_t* g, bf16_t* lds) {
  // 16B direct global->LDS. LDS dest = wave-uniform base + lane*16.
  __builtin_amdgcn_global_load_lds(
      (__attribute__((address_space(1))) unsigned int*)g,
      (__attribute__((address_space(3))) unsigned int*)lds, 16, 0, 0);
}

// ---------------- transpose W: 3x fp32 (4096,128) -> bf16 Wt (384,4096) -------
__global__ void tr_w(const float* __restrict__ w0, const float* __restrict__ w1,
                     const float* __restrict__ w2, bf16_t* __restrict__ wt) {
  __shared__ float tile[32][33];
  const int z = blockIdx.z;
  const float* src = (z == 0) ? w0 : (z == 1) ? w1 : w2;
  bf16_t* dst = wt + (size_t)z * 128 * 4096;
  const int c0 = blockIdx.x * 32;
  const int r0 = blockIdx.y * 32;
  const int tx = threadIdx.x, ty = threadIdx.y;
#pragma unroll
  for (int j = 0; j < 4; ++j)
    tile[ty + 8 * j][tx] = src[(size_t)(r0 + ty + 8 * j) * 128 + c0 + tx];
  __syncthreads();
#pragma unroll
  for (int j = 0; j < 4; ++j)
    dst[(size_t)(c0 + ty + 8 * j) * 4096 + r0 + tx] = (bf16_t)tile[tx][ty + 8 * j];
}

// ---------------- transpose V: bf16 (B,4096,128) -> bf16 Vt (B,128,4096) ------
__global__ void tr_v(const bf16_t* __restrict__ v, bf16_t* __restrict__ vt) {
  __shared__ bf16_t tile[32][33];
  const int b = blockIdx.z;
  const bf16_t* src = v + (size_t)b * 4096 * 128;
  bf16_t* dst = vt + (size_t)b * 128 * 4096;
  const int c0 = blockIdx.x * 32;
  const int r0 = blockIdx.y * 32;
  const int tx = threadIdx.x, ty = threadIdx.y;
#pragma unroll
  for (int j = 0; j < 4; ++j)
    tile[ty + 8 * j][tx] = src[(size_t)(r0 + ty + 8 * j) * 128 + c0 + tx];
  __syncthreads();
#pragma unroll
  for (int j = 0; j < 4; ++j)
    dst[(size_t)(c0 + ty + 8 * j) * 4096 + r0 + tx] = tile[tx][ty + 8 * j];
}

// ---------------- fused QKV projection: fp32 (16384,4096) @ Wt -> 3x bf16 ------
// BM=64, BN=96, BK=64. 256 thr = 4 waves (2M x 2N). Grid 1024 = 256 m x 4 n
// (consecutive bx share the x-panel -> concurrent L2 hits on A).
// LDS 40 KB (sA 2x8K + sB 2x12K) -> 4 blocks/CU = 16 waves/CU (50% occ).
// Counted pipeline per iter: stage B(kt+1) [3 ops], cvt/write A(kt+1)
// (compiler vmcnt(3) retires A regs), issue A(kt+2) [4 ops], 12 MFMA,
// bottom vmcnt(4)+lgkmcnt(0) retires exactly B(kt+1). Never drains to 0.
__device__ __forceinline__ void stage_b(const bf16_t* __restrict__ wt_k,
                                        bf16_t* sBbuf, int tid) {
#pragma unroll
  for (int r = 0; r < 3; ++r) {  // 768 chunks of 16B over 256 threads
    int cid = r * 256 + tid;
    int n = cid >> 3, pc = cid & 7;
    int lc = pc ^ (n & 7);
    async_cp16(wt_k + (size_t)n * 4096 + lc * 8, sBbuf + (size_t)cid * 8);
  }
}

__launch_bounds__(256, 4)
__global__ void qkv_proj(const float* __restrict__ x, const bf16_t* __restrict__ wt,
                         bf16_t* __restrict__ q, bf16_t* __restrict__ k,
                         bf16_t* __restrict__ v) {
  __shared__ __align__(16) bf16_t sA[2][64 * 64];   // 2 x 8 KB, swizzled chunks
  __shared__ __align__(16) bf16_t sB[2][96 * 64];   // 2 x 12 KB, swizzled chunks
  const int tid = threadIdx.x;
  const int w = tid >> 6, lane = tid & 63, lq = lane & 15, quad = lane >> 4;
  const int wr = w >> 1, wc = w & 1;                // wave grid 2 (M) x 2 (N)
  const int mblk = (int)blockIdx.x >> 2;
  const int nblk = (int)blockIdx.x & 3;             // n-slice: cols [nblk*96, +96)
  const int m0 = mblk * 64;
  const bf16_t* wtb = wt + (size_t)nblk * 96 * 4096;

  // A staging: 2 chunks (16B bf16 = 8 fp32) per thread.
  int arow[2], apc[2], alc[2];
#pragma unroll
  for (int r = 0; r < 2; ++r) {
    int ca = r * 256 + tid;
    arow[r] = ca >> 3;
    apc[r] = ca & 7;
    alc[r] = apc[r] ^ (arow[r] & 7);
  }
  const float* xb = x + (size_t)m0 * 4096;

  f32x4 acc[2][3];
#pragma unroll
  for (int i = 0; i < 2; ++i)
#pragma unroll
    for (int j = 0; j < 3; ++j) acc[i][j] = (f32x4){0.f, 0.f, 0.f, 0.f};

  float4 fA[4];
#define LOADA(KT)                                                              \
  {                                                                            \
    _Pragma("unroll") for (int r = 0; r < 2; ++r) {                            \
      const float4* p =                                                        \
          (const float4*)(xb + (size_t)arow[r] * 4096 + (KT)*64 + alc[r] * 8); \
      fA[2 * r] = p[0];                                                        \
      fA[2 * r + 1] = p[1];                                                    \
    }                                                                          \
  }

  // ---- prologue: A(0) regs, B(0)->sB[0], write sA[0], A(1) regs ----
  LOADA(0);
  stage_b(wtb, sB[0], tid);
  __builtin_amdgcn_sched_barrier(0);
#pragma unroll
  for (int r = 0; r < 2; ++r) {
    f32x8 ff = {fA[2 * r].x, fA[2 * r].y, fA[2 * r].z, fA[2 * r].w,
                fA[2 * r + 1].x, fA[2 * r + 1].y, fA[2 * r + 1].z, fA[2 * r + 1].w};
    *(bf16x8*)(sA[0] + arow[r] * 64 + apc[r] * 8) = __builtin_convertvector(ff, bf16x8);
  }
  LOADA(1);
  asm volatile("s_waitcnt vmcnt(4) lgkmcnt(0)" ::: "memory");  // retire B(0)x3
  __builtin_amdgcn_s_barrier();

  for (int kt = 0; kt < 64; ++kt) {
    const int buf = kt & 1;
    // issue B(kt+1) FIRST (must be older than A(kt+2) for the bottom wait)
    const int ktB = (kt < 63) ? kt + 1 : 63;
    stage_b(wtb + ktB * 64, sB[buf ^ 1], tid);
    __builtin_amdgcn_sched_barrier(0);
    // cvt + swizzled ds_write of A(kt+1) (compiler waits vmcnt(3) -> fA ready)
#pragma unroll
    for (int r = 0; r < 2; ++r) {
      f32x8 ff = {fA[2 * r].x, fA[2 * r].y, fA[2 * r].z, fA[2 * r].w,
                  fA[2 * r + 1].x, fA[2 * r + 1].y, fA[2 * r + 1].z, fA[2 * r + 1].w};
      *(bf16x8*)(sA[buf ^ 1] + arow[r] * 64 + apc[r] * 8) =
          __builtin_convertvector(ff, bf16x8);
    }
    // issue A(kt+2) reg loads (clamped at tail)
    const int ktA = (kt < 62) ? kt + 2 : 63;
    LOADA(ktA);
    __builtin_amdgcn_sched_barrier(0);
    // compute tile kt from sA[buf], sB[buf]: 12 MFMA
#pragma unroll
    for (int ks = 0; ks < 2; ++ks) {
      bf16x8 af[2], bfr[3];
      const int cc = ks * 4 + quad;
#pragma unroll
      for (int mt = 0; mt < 2; ++mt) {
        int row = wr * 32 + mt * 16 + lq;
        af[mt] = *(const bf16x8*)(sA[buf] + row * 64 + ((cc ^ (row & 7)) << 3));
      }
#pragma unroll
      for (int nt = 0; nt < 3; ++nt) {
        int n = wc * 48 + nt * 16 + lq;
        bfr[nt] = *(const bf16x8*)(sB[buf] + n * 64 + ((cc ^ (n & 7)) << 3));
      }
#pragma unroll
      for (int mt = 0; mt < 2; ++mt)
#pragma unroll
        for (int nt = 0; nt < 3; ++nt) acc[mt][nt] = MFMA16(af[mt], bfr[nt], acc[mt][nt]);
    }
    // retire exactly B(kt+1) [oldest 3 of 7]; A(kt+2) stays in flight.
    asm volatile("s_waitcnt vmcnt(4) lgkmcnt(0)" ::: "memory");
    __builtin_amdgcn_s_barrier();
  }
#undef LOADA

  // epilogue: global col n -> q/k/v; C/D layout col=lane&15, row=quad*4+reg
#pragma unroll
  for (int mt = 0; mt < 2; ++mt) {
#pragma unroll
    for (int nt = 0; nt < 3; ++nt) {
      int n = nblk * 96 + wc * 48 + nt * 16 + lq;
      bf16_t* dst;
      int nn;
      if (n < 128) { dst = q; nn = n; }
      else if (n < 256) { dst = k; nn = n - 128; }
      else { dst = v; nn = n - 256; }
#pragma unroll
      for (int r = 0; r < 4; ++r) {
        int m = m0 + wr * 32 + mt * 16 + quad * 4 + r;
        dst[(size_t)m * 128 + nn] = (bf16_t)acc[mt][nt][r];
      }
    }
  }
}

// ---------------- flash attention, key-split x2, 2-phase prefetch (R6) --------
// Grid 512: b = x&3, qt = (x>>2)&63, sp = x>>8. Block: 64 Q rows, 256 thr;
// wave w owns rows [w*16, w*16+16). Each block does 32 key-tiles of 64 keys.
__device__ __forceinline__ void stage_kv(const bf16_t* __restrict__ ksrc,
                                         const bf16_t* __restrict__ vsrc,
                                         bf16_t* sKbuf, bf16_t* sVbuf, int tid) {
#pragma unroll
  for (int r = 0; r < 4; ++r) {  // K tile: 1024 chunks, swizzle &15
    int cid = r * 256 + tid;
    int row = cid >> 4, pc = cid & 15;
    int lc = pc ^ (row & 15);
    async_cp16(ksrc + row * 128 + lc * 8, sKbuf + (size_t)cid * 8);
  }
#pragma unroll
  for (int r = 0; r < 4; ++r) {  // Vt tile: 1024 chunks, swizzle &7
    int cid = r * 256 + tid;
    int h = cid >> 3, pc = cid & 7;
    int lc = pc ^ (h & 7);
    async_cp16(vsrc + (size_t)h * 4096 + lc * 8, sVbuf + (size_t)cid * 8);
  }
}

__launch_bounds__(256, 2)
__global__ void flash(const bf16_t* __restrict__ q, const bf16_t* __restrict__ kk,
                      const bf16_t* __restrict__ vt, float* __restrict__ opart,
                      float* __restrict__ mlm, float* __restrict__ mll) {
  __shared__ __align__(16) bf16_t sK[2][64 * 128];  // [key][h], swizzled &15
  __shared__ __align__(16) bf16_t sV[2][128 * 64];  // [h][key], swizzled &7
  __shared__ __align__(16) bf16_t sP[64 * 72];      // [qrow][key], wave-private rows
  const int tid = threadIdx.x;
  const int w = tid >> 6, lane = tid & 63, lq = lane & 15, quad = lane >> 4;
  const int b = blockIdx.x & 3;
  const int qt = (blockIdx.x >> 2) & 63;
  const int sp = blockIdx.x >> 8;
  const int qrow0 = qt * 64;

  bf16x8 qf[4];  // Q A-fragments, full head dim
  {
    const bf16_t* qp = q + ((size_t)b * 4096 + qrow0 + w * 16 + lq) * 128 + quad * 8;
#pragma unroll
    for (int ks = 0; ks < 4; ++ks) qf[ks] = *(const bf16x8*)(qp + ks * 32);
  }

  f32x4 accO[8];
#pragma unroll
  for (int i = 0; i < 8; ++i) accO[i] = (f32x4){0.f, 0.f, 0.f, 0.f};
  float mrow[4] = {-1e30f, -1e30f, -1e30f, -1e30f};
  float lrow[4] = {0.f, 0.f, 0.f, 0.f};

  const bf16_t* kbase = kk + (size_t)b * 4096 * 128;
  const bf16_t* vbase = vt + (size_t)b * 128 * 4096;
  const float SCL = 0.08838834764831845f * 1.4426950408889634f;  // 1/sqrt(128)*log2(e)
  const int it0 = sp * 32;

  stage_kv(kbase + (size_t)it0 * 64 * 128, vbase + it0 * 64, sK[0], sV[0], tid);
  __syncthreads();  // buffer 0 ready

  for (int i = 0; i < 32; ++i) {
    const int buf = i & 1;
    if (i < 31)  // prefetch next tile into other buffer
      stage_kv(kbase + (size_t)(it0 + i + 1) * 64 * 128, vbase + (it0 + i + 1) * 64,
               sK[buf ^ 1], sV[buf ^ 1], tid);

    // --- S = Q K^T: this wave's 16 rows x 64 keys ---
    f32x4 accS[4];
#pragma unroll
    for (int nt = 0; nt < 4; ++nt) accS[nt] = (f32x4){0.f, 0.f, 0.f, 0.f};
    __builtin_amdgcn_s_setprio(1);
#pragma unroll
    for (int ks = 0; ks < 4; ++ks) {
      const int cc = ks * 4 + quad;
#pragma unroll
      for (int nt = 0; nt < 4; ++nt) {
        int row = nt * 16 + lq;
        bf16x8 kf = *(const bf16x8*)(sK[buf] + row * 128 + ((cc ^ (row & 15)) << 3));
        accS[nt] = MFMA16(qf[ks], kf, accS[nt]);
      }
    }
    __builtin_amdgcn_s_setprio(0);

    // --- online softmax: rows = quad*4+r, cols = lane&15 ---
    float mxs[4];
#pragma unroll
    for (int r = 0; r < 4; ++r) {
      float t0 = fmaxf(fmaxf(accS[0][r], accS[1][r]), fmaxf(accS[2][r], accS[3][r]));
#pragma unroll
      for (int msk = 1; msk < 16; msk <<= 1) t0 = fmaxf(t0, __shfl_xor(t0, msk));
      mxs[r] = t0 * SCL;
    }
    bool grow = (mxs[0] > mrow[0]) || (mxs[1] > mrow[1]) ||
                (mxs[2] > mrow[2]) || (mxs[3] > mrow[3]);
    if (__any(grow)) {
      float al[4];
#pragma unroll
      for (int r = 0; r < 4; ++r) {
        float mn = fmaxf(mrow[r], mxs[r]);
        al[r] = exp2f(mrow[r] - mn);
        mrow[r] = mn;
        lrow[r] *= al[r];
      }
#pragma unroll
      for (int ot = 0; ot < 8; ++ot) {
        accO[ot][0] *= al[0]; accO[ot][1] *= al[1];
        accO[ot][2] *= al[2]; accO[ot][3] *= al[3];
      }
    }
    float ps[4] = {0.f, 0.f, 0.f, 0.f};
#pragma unroll
    for (int nt = 0; nt < 4; ++nt)
#pragma unroll
      for (int r = 0; r < 4; ++r) {
        float p = exp2f(fmaf(accS[nt][r], SCL, -mrow[r]));
        accS[nt][r] = p;
        ps[r] += p;
      }
#pragma unroll
    for (int r = 0; r < 4; ++r) {
      float s = ps[r];
#pragma unroll
      for (int msk = 1; msk < 16; msk <<= 1) s += __shfl_xor(s, msk);
      lrow[r] += s;
    }

    // --- write P (bf16) to sP[qrow][key]; rows are wave-private, no barrier ---
#pragma unroll
    for (int nt = 0; nt < 4; ++nt) {
      int key = nt * 16 + lq;
#pragma unroll
      for (int r = 0; r < 4; ++r) {
        int prow = w * 16 + quad * 4 + r;
        sP[prow * 72 + key] = (bf16_t)accS[nt][r];
      }
    }

    // --- O += P V ---
    __builtin_amdgcn_s_setprio(1);
#pragma unroll
    for (int ks2 = 0; ks2 < 2; ++ks2) {
      const int cc = ks2 * 4 + quad;
      bf16x8 pf = *(const bf16x8*)(sP + (w * 16 + lq) * 72 + cc * 8);
#pragma unroll
      for (int ot = 0; ot < 8; ++ot) {
        int h = ot * 16 + lq;
        bf16x8 vf = *(const bf16x8*)(sV[buf] + h * 64 + ((cc ^ (h & 7)) << 3));
        accO[ot] = MFMA16(pf, vf, accO[ot]);
      }
    }
    __builtin_amdgcn_s_setprio(0);
    __syncthreads();  // drains prefetch vmcnt + all reads of buf; swap buffers
  }

  // --- store fp32 partials (unnormalized) + m,l ---
  float* op = opart + ((size_t)(sp * 4 + b) * 4096 + qrow0 + w * 16) * 128;
#pragma unroll
  for (int ot = 0; ot < 8; ++ot)
#pragma unroll
    for (int r = 0; r < 4; ++r)
      op[(size_t)(quad * 4 + r) * 128 + ot * 16 + lq] = accO[ot][r];
  if (lq == 0) {
#pragma unroll
    for (int r = 0; r < 4; ++r) {
      size_t idx = (size_t)(sp * 4 + b) * 4096 + qrow0 + w * 16 + quad * 4 + r;
      mlm[idx] = mrow[r];
      mll[idx] = lrow[r];
    }
  }
}

// ---------------- merge the 2 key-splits --------------------------------------
__global__ void merge(const float* __restrict__ opart, const float* __restrict__ mlm,
                      const float* __restrict__ mll, float* __restrict__ out) {
  const int idx = blockIdx.x * 256 + threadIdx.x;  // 2M elements
  const int h = idx & 127;
  const int row = idx >> 7;  // b*4096 + t
  float m0 = mlm[row], m1 = mlm[16384 + row];
  float l0 = mll[row], l1 = mll[16384 + row];
  float M = fmaxf(m0, m1);
  float w0 = exp2f(m0 - M), w1 = exp2f(m1 - M);
  float L = w0 * l0 + w1 * l1;
  float acc = w0 * opart[(size_t)row * 128 + h] +
              w1 * opart[((size_t)16384 + row) * 128 + h];
  out[idx] = acc / L;
}

extern "C" void kernel_launch(void* const* d_in, const int* in_sizes, int n_in,
                              void* d_out, int out_size, void* d_ws, size_t ws_size,
                              hipStream_t stream) {
  (void)in_sizes; (void)n_in; (void)out_size; (void)ws_size;
  const float* x  = (const float*)d_in[0];
  const float* wq = (const float*)d_in[1];
  const float* wk = (const float*)d_in[2];
  const float* wv = (const float*)d_in[3];

  char* ws = (char*)d_ws;
  bf16_t* wt  = (bf16_t*)ws;                         ws += (size_t)384 * 4096 * 2;
  bf16_t* qb  = (bf16_t*)ws;                         ws += (size_t)16384 * 128 * 2;
  bf16_t* kb  = (bf16_t*)ws;                         ws += (size_t)16384 * 128 * 2;
  bf16_t* vb  = (bf16_t*)ws;                         ws += (size_t)16384 * 128 * 2;
  bf16_t* vtb = (bf16_t*)ws;                         ws += (size_t)16384 * 128 * 2;
  float*  opart = (float*)ws;                        ws += (size_t)2 * 16384 * 128 * 4;
  float*  mlm = (float*)ws;                          ws += (size_t)2 * 16384 * 4;
  float*  mll = (float*)ws;
  float*  ob  = (float*)d_out;

  dim3 tb(32, 8, 1);
  tr_w<<<dim3(4, 128, 3), tb, 0, stream>>>(wq, wk, wv, wt);
  qkv_proj<<<dim3(1024), dim3(256), 0, stream>>>(x, wt, qb, kb, vb);
  tr_v<<<dim3(4, 128, 4), tb, 0, stream>>>(vb, vtb);
  flash<<<dim3(512), dim3(256), 0, stream>>>(qb, kb, vtb, opart, mlm, mll);
  merge<<<dim3(8192), dim3(256), 0, stream>>>(opart, mlm, mll, ob);
}

// Round 7
// 539.290 us; speedup vs baseline: 1.0548x; 1.0548x over previous
//
#include <hip/hip_runtime.h>

// SelfAttention: B=4, T=4096, D=4096, H=128. fp32 in/out, bf16 MFMA compute.
// R10: TRANSPOSED qkv (qkv_t): O[384][16384] = Wt @ x^T. A=Wt is the only
// LDS operand (L2-hot, 96 KB dbuf); B=x per-lane register loads (read once,
// barrier-free); Q/K stored natively [t][h] (packed b64), V stored transposed
// -> tr_v deleted. flash = R6 except V source stride (vt is now [128][16384]).
// merge unchanged. No sched_barrier anywhere (m141 lesson).

typedef __bf16 bf16_t;
typedef bf16_t bf16x4 __attribute__((ext_vector_type(4)));
typedef bf16_t bf16x8 __attribute__((ext_vector_type(8)));
typedef float f32x4 __attribute__((ext_vector_type(4)));
typedef float f32x8 __attribute__((ext_vector_type(8)));

#define MFMA16(A, B, C) __builtin_amdgcn_mfma_f32_16x16x32_bf16((A), (B), (C), 0, 0, 0)

__device__ __forceinline__ void async_cp16(const bf16_t* g, bf16_t* lds) {
  // 16B direct global->LDS. LDS dest = wave-uniform base + lane*16.
  __builtin_amdgcn_global_load_lds(
      (__attribute__((address_space(1))) unsigned int*)g,
      (__attribute__((address_space(3))) unsigned int*)lds, 16, 0, 0);
}

// ---------------- transpose W: 3x fp32 (4096,128) -> bf16 Wt (384,4096) -------
__global__ void tr_w(const float* __restrict__ w0, const float* __restrict__ w1,
                     const float* __restrict__ w2, bf16_t* __restrict__ wt) {
  __shared__ float tile[32][33];
  const int z = blockIdx.z;
  const float* src = (z == 0) ? w0 : (z == 1) ? w1 : w2;
  bf16_t* dst = wt + (size_t)z * 128 * 4096;
  const int c0 = blockIdx.x * 32;
  const int r0 = blockIdx.y * 32;
  const int tx = threadIdx.x, ty = threadIdx.y;
#pragma unroll
  for (int j = 0; j < 4; ++j)
    tile[ty + 8 * j][tx] = src[(size_t)(r0 + ty + 8 * j) * 128 + c0 + tx];
  __syncthreads();
#pragma unroll
  for (int j = 0; j < 4; ++j)
    dst[(size_t)(c0 + ty + 8 * j) * 4096 + r0 + tx] = (bf16_t)tile[tx][ty + 8 * j];
}

// ---------------- transposed QKV: Wt[384][4096] @ x^T -> Q,K [t][h], Vt[h][t] --
// Grid 256 x 512 thr (8 waves = 4 h-waves x 2 t-waves). Per block: all 384 h,
// 64 t-cols, K-loop 64 x BK=64.
//   A (Wt): LDS dbuf 2x48 KB via gload_lds, swizzle ^(n&7). L2-hot.
//   B (x):  per-lane fp32 register loads (frag = x[t][k..k+8], 32 B), cvt bf16.
// Wave w: wr=w>>1 owns h [wr*96,+96) (6 mt frags), wc=w&1 owns t [wc*32,+32)
// (2 nt frags). acc[6][2]. 24 MFMA/iter/wave.
// Queue discipline (counted, never 0): iter top queue=[X(kt):8]; +stage W(kt+1)
// [6]; cvt fX -> compiler vmcnt(6) retires X(kt); +LOADX(kt+1) [8]; MFMA;
// bottom vmcnt(8)+lgkmcnt(0) retires W(kt+1); s_barrier.
__device__ __forceinline__ void stage_w(const bf16_t* __restrict__ wt_k,
                                        bf16_t* sWbuf, int tid) {
#pragma unroll
  for (int r = 0; r < 6; ++r) {  // 3072 chunks of 16B over 512 threads
    int cid = r * 512 + tid;
    int n = cid >> 3, pc = cid & 7;
    int lc = pc ^ (n & 7);
    async_cp16(wt_k + (size_t)n * 4096 + lc * 8, sWbuf + (size_t)cid * 8);
  }
}

__launch_bounds__(512, 1)
__global__ void qkv_t(const float* __restrict__ x, const bf16_t* __restrict__ wt,
                      bf16_t* __restrict__ q, bf16_t* __restrict__ k,
                      bf16_t* __restrict__ vt) {
  __shared__ __align__(16) bf16_t sW[2][384 * 64];  // 2 x 48 KB
  const int tid = threadIdx.x;
  const int w = tid >> 6, lane = tid & 63, lq = lane & 15, quad = lane >> 4;
  const int wr = w >> 1, wc = w & 1;
  const int t0 = blockIdx.x * 64;

  // x row base per (nt): lane reads x[t0 + wc*32 + nt*16 + lq][...k + quad*8]
  const float* xb[2];
#pragma unroll
  for (int nt = 0; nt < 2; ++nt)
    xb[nt] = x + (size_t)(t0 + wc * 32 + nt * 16 + lq) * 4096 + quad * 8;

  f32x4 acc[6][2];
#pragma unroll
  for (int i = 0; i < 6; ++i)
#pragma unroll
    for (int j = 0; j < 2; ++j) acc[i][j] = (f32x4){0.f, 0.f, 0.f, 0.f};

  float4 fX[8];  // [nt][ks][half], static indices
#define LOADX(KT)                                                    \
  {                                                                  \
    _Pragma("unroll") for (int nt = 0; nt < 2; ++nt) {               \
      _Pragma("unroll") for (int ks = 0; ks < 2; ++ks) {             \
        const float4* p = (const float4*)(xb[nt] + (KT)*64 + ks*32); \
        fX[(nt * 2 + ks) * 2 + 0] = p[0];                            \
        fX[(nt * 2 + ks) * 2 + 1] = p[1];                            \
      }                                                              \
    }                                                                \
  }

  // ---- prologue: W(0)->sW[0] [6], X(0) [8]; retire W(0) ----
  stage_w(wt, sW[0], tid);
  LOADX(0);
  asm volatile("s_waitcnt vmcnt(8)" ::: "memory");
  __builtin_amdgcn_s_barrier();

  for (int kt = 0; kt < 64; ++kt) {
    const int buf = kt & 1;
    // stage W(kt+1) (clamped dummy at tail keeps counts uniform)
    const int ktW = (kt < 63) ? kt + 1 : 63;
    stage_w(wt + ktW * 64, sW[buf ^ 1], tid);
    // cvt B-frags from fX(kt): compiler inserts vmcnt(6) (retires X(kt))
    bf16x8 bfr[4];
#pragma unroll
    for (int nt = 0; nt < 2; ++nt)
#pragma unroll
      for (int ks = 0; ks < 2; ++ks) {
        float4 a = fX[(nt * 2 + ks) * 2 + 0], b = fX[(nt * 2 + ks) * 2 + 1];
        f32x8 ff = {a.x, a.y, a.z, a.w, b.x, b.y, b.z, b.w};
        bfr[nt * 2 + ks] = __builtin_convertvector(ff, bf16x8);
      }
    // issue X(kt+1) (after all fX uses; register WAR keeps order)
    const int ktX = (kt < 63) ? kt + 1 : 63;
    LOADX(ktX);
    // compute: A-frags from sW[buf], 24 MFMA
#pragma unroll
    for (int ks = 0; ks < 2; ++ks) {
      const int cc = ks * 4 + quad;
      bf16x8 af[6];
#pragma unroll
      for (int mt = 0; mt < 6; ++mt) {
        int n = wr * 96 + mt * 16 + lq;
        af[mt] = *(const bf16x8*)(sW[buf] + n * 64 + ((cc ^ (n & 7)) << 3));
      }
#pragma unroll
      for (int mt = 0; mt < 6; ++mt)
#pragma unroll
        for (int nt = 0; nt < 2; ++nt)
          acc[mt][nt] = MFMA16(af[mt], bfr[nt * 2 + ks], acc[mt][nt]);
    }
    // retire W(kt+1) [oldest 6 of 14]; X(kt+1) stays in flight.
    asm volatile("s_waitcnt vmcnt(8) lgkmcnt(0)" ::: "memory");
    __builtin_amdgcn_s_barrier();
  }
#undef LOADX

  // epilogue: D row = h-global = wr*96 + mt*16 + quad*4 + r; col t = lane&15.
  // Q/K: 4 contiguous h per lane -> packed b64 store. V: h-major scatter to vt.
#pragma unroll
  for (int mt = 0; mt < 6; ++mt) {
    const int hg0 = wr * 96 + mt * 16 + quad * 4;  // frag never straddles 128/256
#pragma unroll
    for (int nt = 0; nt < 2; ++nt) {
      const int t = t0 + wc * 32 + nt * 16 + lq;
      if (hg0 < 256) {
        bf16_t* dst = (hg0 < 128) ? (q + (size_t)t * 128 + hg0)
                                  : (k + (size_t)t * 128 + (hg0 - 128));
        bf16x4 pk;
#pragma unroll
        for (int r = 0; r < 4; ++r) pk[r] = (bf16_t)acc[mt][nt][r];
        *(bf16x4*)dst = pk;
      } else {
#pragma unroll
        for (int r = 0; r < 4; ++r)
          vt[(size_t)(hg0 - 256 + r) * 16384 + t] = (bf16_t)acc[mt][nt][r];
      }
    }
  }
}

// ---------------- flash attention, key-split x2, 2-phase prefetch (R6) --------
// vt layout now [128][16384] (h-major, t global). Only the V staging lines
// changed vs R6 (stride 4096 -> 16384, base b*4096).
__device__ __forceinline__ void stage_kv(const bf16_t* __restrict__ ksrc,
                                         const bf16_t* __restrict__ vsrc,
                                         bf16_t* sKbuf, bf16_t* sVbuf, int tid) {
#pragma unroll
  for (int r = 0; r < 4; ++r) {  // K tile: 1024 chunks, swizzle &15
    int cid = r * 256 + tid;
    int row = cid >> 4, pc = cid & 15;
    int lc = pc ^ (row & 15);
    async_cp16(ksrc + row * 128 + lc * 8, sKbuf + (size_t)cid * 8);
  }
#pragma unroll
  for (int r = 0; r < 4; ++r) {  // Vt tile: 1024 chunks, swizzle &7
    int cid = r * 256 + tid;
    int h = cid >> 3, pc = cid & 7;
    int lc = pc ^ (h & 7);
    async_cp16(vsrc + (size_t)h * 16384 + lc * 8, sVbuf + (size_t)cid * 8);
  }
}

__launch_bounds__(256, 2)
__global__ void flash(const bf16_t* __restrict__ q, const bf16_t* __restrict__ kk,
                      const bf16_t* __restrict__ vt, float* __restrict__ opart,
                      float* __restrict__ mlm, float* __restrict__ mll) {
  __shared__ __align__(16) bf16_t sK[2][64 * 128];  // [key][h], swizzled &15
  __shared__ __align__(16) bf16_t sV[2][128 * 64];  // [h][key], swizzled &7
  __shared__ __align__(16) bf16_t sP[64 * 72];      // [qrow][key], wave-private rows
  const int tid = threadIdx.x;
  const int w = tid >> 6, lane = tid & 63, lq = lane & 15, quad = lane >> 4;
  const int b = blockIdx.x & 3;
  const int qt = (blockIdx.x >> 2) & 63;
  const int sp = blockIdx.x >> 8;
  const int qrow0 = qt * 64;

  bf16x8 qf[4];  // Q A-fragments, full head dim
  {
    const bf16_t* qp = q + ((size_t)b * 4096 + qrow0 + w * 16 + lq) * 128 + quad * 8;
#pragma unroll
    for (int ks = 0; ks < 4; ++ks) qf[ks] = *(const bf16x8*)(qp + ks * 32);
  }

  f32x4 accO[8];
#pragma unroll
  for (int i = 0; i < 8; ++i) accO[i] = (f32x4){0.f, 0.f, 0.f, 0.f};
  float mrow[4] = {-1e30f, -1e30f, -1e30f, -1e30f};
  float lrow[4] = {0.f, 0.f, 0.f, 0.f};

  const bf16_t* kbase = kk + (size_t)b * 4096 * 128;
  const bf16_t* vbase = vt + (size_t)b * 4096;  // vt[h][t_global]
  const float SCL = 0.08838834764831845f * 1.4426950408889634f;  // 1/sqrt(128)*log2(e)
  const int it0 = sp * 32;

  stage_kv(kbase + (size_t)it0 * 64 * 128, vbase + it0 * 64, sK[0], sV[0], tid);
  __syncthreads();  // buffer 0 ready

  for (int i = 0; i < 32; ++i) {
    const int buf = i & 1;
    if (i < 31)  // prefetch next tile into other buffer
      stage_kv(kbase + (size_t)(it0 + i + 1) * 64 * 128, vbase + (it0 + i + 1) * 64,
               sK[buf ^ 1], sV[buf ^ 1], tid);

    // --- S = Q K^T: this wave's 16 rows x 64 keys ---
    f32x4 accS[4];
#pragma unroll
    for (int nt = 0; nt < 4; ++nt) accS[nt] = (f32x4){0.f, 0.f, 0.f, 0.f};
    __builtin_amdgcn_s_setprio(1);
#pragma unroll
    for (int ks = 0; ks < 4; ++ks) {
      const int cc = ks * 4 + quad;
#pragma unroll
      for (int nt = 0; nt < 4; ++nt) {
        int row = nt * 16 + lq;
        bf16x8 kf = *(const bf16x8*)(sK[buf] + row * 128 + ((cc ^ (row & 15)) << 3));
        accS[nt] = MFMA16(qf[ks], kf, accS[nt]);
      }
    }
    __builtin_amdgcn_s_setprio(0);

    // --- online softmax: rows = quad*4+r, cols = lane&15 ---
    float mxs[4];
#pragma unroll
    for (int r = 0; r < 4; ++r) {
      float t0 = fmaxf(fmaxf(accS[0][r], accS[1][r]), fmaxf(accS[2][r], accS[3][r]));
#pragma unroll
      for (int msk = 1; msk < 16; msk <<= 1) t0 = fmaxf(t0, __shfl_xor(t0, msk));
      mxs[r] = t0 * SCL;
    }
    bool grow = (mxs[0] > mrow[0]) || (mxs[1] > mrow[1]) ||
                (mxs[2] > mrow[2]) || (mxs[3] > mrow[3]);
    if (__any(grow)) {
      float al[4];
#pragma unroll
      for (int r = 0; r < 4; ++r) {
        float mn = fmaxf(mrow[r], mxs[r]);
        al[r] = exp2f(mrow[r] - mn);
        mrow[r] = mn;
        lrow[r] *= al[r];
      }
#pragma unroll
      for (int ot = 0; ot < 8; ++ot) {
        accO[ot][0] *= al[0]; accO[ot][1] *= al[1];
        accO[ot][2] *= al[2]; accO[ot][3] *= al[3];
      }
    }
    float ps[4] = {0.f, 0.f, 0.f, 0.f};
#pragma unroll
    for (int nt = 0; nt < 4; ++nt)
#pragma unroll
      for (int r = 0; r < 4; ++r) {
        float p = exp2f(fmaf(accS[nt][r], SCL, -mrow[r]));
        accS[nt][r] = p;
        ps[r] += p;
      }
#pragma unroll
    for (int r = 0; r < 4; ++r) {
      float s = ps[r];
#pragma unroll
      for (int msk = 1; msk < 16; msk <<= 1) s += __shfl_xor(s, msk);
      lrow[r] += s;
    }

    // --- write P (bf16) to sP[qrow][key]; rows are wave-private, no barrier ---
#pragma unroll
    for (int nt = 0; nt < 4; ++nt) {
      int key = nt * 16 + lq;
#pragma unroll
      for (int r = 0; r < 4; ++r) {
        int prow = w * 16 + quad * 4 + r;
        sP[prow * 72 + key] = (bf16_t)accS[nt][r];
      }
    }

    // --- O += P V ---
    __builtin_amdgcn_s_setprio(1);
#pragma unroll
    for (int ks2 = 0; ks2 < 2; ++ks2) {
      const int cc = ks2 * 4 + quad;
      bf16x8 pf = *(const bf16x8*)(sP + (w * 16 + lq) * 72 + cc * 8);
#pragma unroll
      for (int ot = 0; ot < 8; ++ot) {
        int h = ot * 16 + lq;
        bf16x8 vf = *(const bf16x8*)(sV[buf] + h * 64 + ((cc ^ (h & 7)) << 3));
        accO[ot] = MFMA16(pf, vf, accO[ot]);
      }
    }
    __builtin_amdgcn_s_setprio(0);
    __syncthreads();  // drains prefetch vmcnt + all reads of buf; swap buffers
  }

  // --- store fp32 partials (unnormalized) + m,l ---
  float* op = opart + ((size_t)(sp * 4 + b) * 4096 + qrow0 + w * 16) * 128;
#pragma unroll
  for (int ot = 0; ot < 8; ++ot)
#pragma unroll
    for (int r = 0; r < 4; ++r)
      op[(size_t)(quad * 4 + r) * 128 + ot * 16 + lq] = accO[ot][r];
  if (lq == 0) {
#pragma unroll
    for (int r = 0; r < 4; ++r) {
      size_t idx = (size_t)(sp * 4 + b) * 4096 + qrow0 + w * 16 + quad * 4 + r;
      mlm[idx] = mrow[r];
      mll[idx] = lrow[r];
    }
  }
}

// ---------------- merge the 2 key-splits --------------------------------------
__global__ void merge(const float* __restrict__ opart, const float* __restrict__ mlm,
                      const float* __restrict__ mll, float* __restrict__ out) {
  const int idx = blockIdx.x * 256 + threadIdx.x;  // 2M elements
  const int h = idx & 127;
  const int row = idx >> 7;  // b*4096 + t
  float m0 = mlm[row], m1 = mlm[16384 + row];
  float l0 = mll[row], l1 = mll[16384 + row];
  float M = fmaxf(m0, m1);
  float w0 = exp2f(m0 - M), w1 = exp2f(m1 - M);
  float L = w0 * l0 + w1 * l1;
  float acc = w0 * opart[(size_t)row * 128 + h] +
              w1 * opart[((size_t)16384 + row) * 128 + h];
  out[idx] = acc / L;
}

extern "C" void kernel_launch(void* const* d_in, const int* in_sizes, int n_in,
                              void* d_out, int out_size, void* d_ws, size_t ws_size,
                              hipStream_t stream) {
  (void)in_sizes; (void)n_in; (void)out_size; (void)ws_size;
  const float* x  = (const float*)d_in[0];
  const float* wq = (const float*)d_in[1];
  const float* wk = (const float*)d_in[2];
  const float* wv = (const float*)d_in[3];

  char* ws = (char*)d_ws;
  bf16_t* wt  = (bf16_t*)ws;                         ws += (size_t)384 * 4096 * 2;
  bf16_t* qb  = (bf16_t*)ws;                         ws += (size_t)16384 * 128 * 2;
  bf16_t* kb  = (bf16_t*)ws;                         ws += (size_t)16384 * 128 * 2;
  bf16_t* vtb = (bf16_t*)ws;                         ws += (size_t)16384 * 128 * 2;
  float*  opart = (float*)ws;                        ws += (size_t)2 * 16384 * 128 * 4;
  float*  mlm = (float*)ws;                          ws += (size_t)2 * 16384 * 4;
  float*  mll = (float*)ws;
  float*  ob  = (float*)d_out;

  dim3 tb(32, 8, 1);
  tr_w<<<dim3(4, 128, 3), tb, 0, stream>>>(wq, wk, wv, wt);
  qkv_t<<<dim3(256), dim3(512), 0, stream>>>(x, wt, qb, kb, vtb);
  flash<<<dim3(512), dim3(256), 0, stream>>>(qb, kb, vtb, opart, mlm, mll);
  merge<<<dim3(8192), dim3(256), 0, stream>>>(opart, mlm, mll, ob);
}

// Round 8
// 506.658 us; speedup vs baseline: 1.1228x; 1.0644x over previous
//
#include <hip/hip_runtime.h>

// SelfAttention: B=4, T=4096, D=4096, H=128. fp32 in/out, bf16 MFMA compute.
// R11: EPOCH-COUNT round. qkv_ks: BM=128 x BN=384(full) x BK=64, K-split x2,
// grid 256 (1 blk/CU) -> 32 stage/barrier epochs per CU (vs 128 in R6; all
// prior designs ~2.5us/epoch). fp32 partials + qkred/vred merge (vred also
// does the V transpose). flash/tr_w/merge unchanged from R10.

typedef __bf16 bf16_t;
typedef bf16_t bf16x4 __attribute__((ext_vector_type(4)));
typedef bf16_t bf16x8 __attribute__((ext_vector_type(8)));
typedef float f32x4 __attribute__((ext_vector_type(4)));
typedef float f32x8 __attribute__((ext_vector_type(8)));

#define MFMA16(A, B, C) __builtin_amdgcn_mfma_f32_16x16x32_bf16((A), (B), (C), 0, 0, 0)

__device__ __forceinline__ void async_cp16(const bf16_t* g, bf16_t* lds) {
  __builtin_amdgcn_global_load_lds(
      (__attribute__((address_space(1))) unsigned int*)g,
      (__attribute__((address_space(3))) unsigned int*)lds, 16, 0, 0);
}

// ---------------- transpose W: 3x fp32 (4096,128) -> bf16 Wt (384,4096) -------
__global__ void tr_w(const float* __restrict__ w0, const float* __restrict__ w1,
                     const float* __restrict__ w2, bf16_t* __restrict__ wt) {
  __shared__ float tile[32][33];
  const int z = blockIdx.z;
  const float* src = (z == 0) ? w0 : (z == 1) ? w1 : w2;
  bf16_t* dst = wt + (size_t)z * 128 * 4096;
  const int c0 = blockIdx.x * 32;
  const int r0 = blockIdx.y * 32;
  const int tx = threadIdx.x, ty = threadIdx.y;
#pragma unroll
  for (int j = 0; j < 4; ++j)
    tile[ty + 8 * j][tx] = src[(size_t)(r0 + ty + 8 * j) * 128 + c0 + tx];
  __syncthreads();
#pragma unroll
  for (int j = 0; j < 4; ++j)
    dst[(size_t)(c0 + ty + 8 * j) * 4096 + r0 + tx] = (bf16_t)tile[tx][ty + 8 * j];
}

// ---------------- K-split QKV: x[16384][4096] @ Wt^T -> fp32 partials ---------
// Grid 256: mblk = bx>>1 (BM=128), sp = bx&1 (K-half). 512 thr = 8 waves
// (2M x 4N); per-wave 64x96, acc[4][6], 48 MFMA/epoch. 32 epochs of BK=64.
// LDS 128 KB: sA 2x16K (x-tile bf16, swizzled ^(row&7)), sB 2x48K (Wt full-N).
// R6-verbatim counted discipline: per epoch issue B(kt+1) [6 ops], ds_write
// A(kt+1) (compiler vmcnt(6) retires the 4 A regs), issue A(kt+2) [4 ops],
// MFMA, bottom vmcnt(4)+lgkmcnt(0) retires exactly B(kt+1). Never drains to 0.
__device__ __forceinline__ void stage_b384(const bf16_t* __restrict__ wt_k,
                                           bf16_t* sBbuf, int tid) {
#pragma unroll
  for (int r = 0; r < 6; ++r) {  // 3072 chunks of 16B over 512 threads
    int cid = r * 512 + tid;
    int n = cid >> 3, pc = cid & 7;
    int lc = pc ^ (n & 7);
    async_cp16(wt_k + (size_t)n * 4096 + lc * 8, sBbuf + (size_t)cid * 8);
  }
}

__launch_bounds__(512, 1)
__global__ void qkv_ks(const float* __restrict__ x, const bf16_t* __restrict__ wt,
                       float* __restrict__ opart) {
  __shared__ __align__(16) bf16_t sA[2][128 * 64];  // 2 x 16 KB
  __shared__ __align__(16) bf16_t sB[2][384 * 64];  // 2 x 48 KB
  const int tid = threadIdx.x;
  const int w = tid >> 6, lane = tid & 63, lq = lane & 15, quad = lane >> 4;
  const int wr = w >> 2, wc = w & 3;  // wave grid 2 (M) x 4 (N)
  const int mblk = (int)blockIdx.x >> 1;
  const int sp = (int)blockIdx.x & 1;  // K-half
  const int m0 = mblk * 128;
  const int kt0 = sp * 32;

  // A staging: 2 chunks (16B bf16 = 8 fp32) per thread, rows 0..127.
  int arow[2], apc[2], alc[2];
#pragma unroll
  for (int r = 0; r < 2; ++r) {
    int ca = r * 512 + tid;
    arow[r] = ca >> 3;
    apc[r] = ca & 7;
    alc[r] = apc[r] ^ (arow[r] & 7);
  }
  const float* xb = x + (size_t)m0 * 4096;

  f32x4 acc[4][6];
#pragma unroll
  for (int i = 0; i < 4; ++i)
#pragma unroll
    for (int j = 0; j < 6; ++j) acc[i][j] = (f32x4){0.f, 0.f, 0.f, 0.f};

  float4 fA[4];
#define LOADA(KT)                                                              \
  {                                                                            \
    _Pragma("unroll") for (int r = 0; r < 2; ++r) {                            \
      const float4* p =                                                        \
          (const float4*)(xb + (size_t)arow[r] * 4096 + (KT)*64 + alc[r] * 8); \
      fA[2 * r] = p[0];                                                        \
      fA[2 * r + 1] = p[1];                                                    \
    }                                                                          \
  }

  // ---- prologue: A(0) regs, B(0)->sB[0], write sA[0], A(1) regs ----
  LOADA(kt0);
  stage_b384(wt + kt0 * 64, sB[0], tid);
  __builtin_amdgcn_sched_barrier(0);
#pragma unroll
  for (int r = 0; r < 2; ++r) {
    f32x8 ff = {fA[2 * r].x, fA[2 * r].y, fA[2 * r].z, fA[2 * r].w,
                fA[2 * r + 1].x, fA[2 * r + 1].y, fA[2 * r + 1].z, fA[2 * r + 1].w};
    *(bf16x8*)(sA[0] + arow[r] * 64 + apc[r] * 8) = __builtin_convertvector(ff, bf16x8);
  }
  LOADA(kt0 + 1);
  asm volatile("s_waitcnt vmcnt(4) lgkmcnt(0)" ::: "memory");  // retire B(0)
  __builtin_amdgcn_s_barrier();

  for (int k2 = 0; k2 < 32; ++k2) {
    const int kt = kt0 + k2;
    const int buf = k2 & 1;
    // issue B(kt+1) FIRST (clamped dummy at split tail keeps counts uniform)
    const int ktB = (k2 < 31) ? kt + 1 : kt;
    stage_b384(wt + ktB * 64, sB[buf ^ 1], tid);
    __builtin_amdgcn_sched_barrier(0);
    // cvt + swizzled ds_write of A(kt+1) (compiler waits vmcnt(6) -> fA ready)
#pragma unroll
    for (int r = 0; r < 2; ++r) {
      f32x8 ff = {fA[2 * r].x, fA[2 * r].y, fA[2 * r].z, fA[2 * r].w,
                  fA[2 * r + 1].x, fA[2 * r + 1].y, fA[2 * r + 1].z, fA[2 * r + 1].w};
      *(bf16x8*)(sA[buf ^ 1] + arow[r] * 64 + apc[r] * 8) =
          __builtin_convertvector(ff, bf16x8);
    }
    // issue A(kt+2) reg loads (clamped within global K)
    const int ktA = (k2 < 30) ? kt + 2 : kt0 + 31;
    LOADA(ktA);
    __builtin_amdgcn_sched_barrier(0);
    // compute tile kt from sA[buf], sB[buf]: 48 MFMA/wave
#pragma unroll
    for (int ks = 0; ks < 2; ++ks) {
      bf16x8 af[4], bfr[6];
      const int cc = ks * 4 + quad;
#pragma unroll
      for (int mt = 0; mt < 4; ++mt) {
        int row = wr * 64 + mt * 16 + lq;
        af[mt] = *(const bf16x8*)(sA[buf] + row * 64 + ((cc ^ (row & 7)) << 3));
      }
#pragma unroll
      for (int nt = 0; nt < 6; ++nt) {
        int n = wc * 96 + nt * 16 + lq;
        bfr[nt] = *(const bf16x8*)(sB[buf] + n * 64 + ((cc ^ (n & 7)) << 3));
      }
#pragma unroll
      for (int mt = 0; mt < 4; ++mt)
#pragma unroll
        for (int nt = 0; nt < 6; ++nt) acc[mt][nt] = MFMA16(af[mt], bfr[nt], acc[mt][nt]);
    }
    // retire exactly B(kt+1) [oldest 6 of 10]; A(kt+2) stays in flight.
    asm volatile("s_waitcnt vmcnt(4) lgkmcnt(0)" ::: "memory");
    __builtin_amdgcn_s_barrier();
  }
#undef LOADA

  // epilogue: fp32 partial store, op[sp][m][n], coalesced over lq (n).
  float* op = opart + (size_t)sp * 16384 * 384;
#pragma unroll
  for (int mt = 0; mt < 4; ++mt) {
#pragma unroll
    for (int nt = 0; nt < 6; ++nt) {
      int n = wc * 96 + nt * 16 + lq;
#pragma unroll
      for (int r = 0; r < 4; ++r) {
        int m = m0 + wr * 64 + mt * 16 + quad * 4 + r;
        op[(size_t)m * 384 + n] = acc[mt][nt][r];
      }
    }
  }
}

// ---------------- reduce the 2 K-splits: cols 0..255 -> q,k ([t][128] bf16) ----
__global__ void qkred(const float* __restrict__ opart, bf16_t* __restrict__ q,
                      bf16_t* __restrict__ k) {
  const int tid = threadIdx.x;
  const int t = blockIdx.x * 4 + (tid >> 6);
  const int n4 = (tid & 63) * 4;  // 0..252
  const float* p0 = opart + (size_t)t * 384 + n4;
  const float* p1 = p0 + (size_t)16384 * 384;
  float4 a = *(const float4*)p0, b = *(const float4*)p1;
  bf16x4 o;
  o[0] = (bf16_t)(a.x + b.x);
  o[1] = (bf16_t)(a.y + b.y);
  o[2] = (bf16_t)(a.z + b.z);
  o[3] = (bf16_t)(a.w + b.w);
  if (n4 < 128)
    *(bf16x4*)(q + (size_t)t * 128 + n4) = o;
  else
    *(bf16x4*)(k + (size_t)t * 128 + (n4 - 128)) = o;
}

// ---------------- reduce cols 256..383 + transpose -> vt [128][16384] bf16 ----
__global__ void vred(const float* __restrict__ opart, bf16_t* __restrict__ vt) {
  __shared__ bf16_t tile[32][33];
  const int c0 = blockIdx.x * 32;   // 0..96 (v-col)
  const int t0 = blockIdx.y * 32;   // 0..16352
  const int tx = threadIdx.x, ty = threadIdx.y;
  const float* p0 = opart + 256;
  const float* p1 = p0 + (size_t)16384 * 384;
#pragma unroll
  for (int j = 0; j < 4; ++j) {
    size_t idx = (size_t)(t0 + ty + 8 * j) * 384 + c0 + tx;
    tile[ty + 8 * j][tx] = (bf16_t)(p0[idx] + p1[idx]);
  }
  __syncthreads();
#pragma unroll
  for (int j = 0; j < 4; ++j)
    vt[(size_t)(c0 + ty + 8 * j) * 16384 + t0 + tx] = tile[tx][ty + 8 * j];
}

// ---------------- flash attention, key-split x2, 2-phase prefetch -------------
// vt layout [128][16384] (h-major, global t).
__device__ __forceinline__ void stage_kv(const bf16_t* __restrict__ ksrc,
                                         const bf16_t* __restrict__ vsrc,
                                         bf16_t* sKbuf, bf16_t* sVbuf, int tid) {
#pragma unroll
  for (int r = 0; r < 4; ++r) {  // K tile: 1024 chunks, swizzle &15
    int cid = r * 256 + tid;
    int row = cid >> 4, pc = cid & 15;
    int lc = pc ^ (row & 15);
    async_cp16(ksrc + row * 128 + lc * 8, sKbuf + (size_t)cid * 8);
  }
#pragma unroll
  for (int r = 0; r < 4; ++r) {  // Vt tile: 1024 chunks, swizzle &7
    int cid = r * 256 + tid;
    int h = cid >> 3, pc = cid & 7;
    int lc = pc ^ (h & 7);
    async_cp16(vsrc + (size_t)h * 16384 + lc * 8, sVbuf + (size_t)cid * 8);
  }
}

__launch_bounds__(256, 2)
__global__ void flash(const bf16_t* __restrict__ q, const bf16_t* __restrict__ kk,
                      const bf16_t* __restrict__ vt, float* __restrict__ opart,
                      float* __restrict__ mlm, float* __restrict__ mll) {
  __shared__ __align__(16) bf16_t sK[2][64 * 128];
  __shared__ __align__(16) bf16_t sV[2][128 * 64];
  __shared__ __align__(16) bf16_t sP[64 * 72];
  const int tid = threadIdx.x;
  const int w = tid >> 6, lane = tid & 63, lq = lane & 15, quad = lane >> 4;
  const int b = blockIdx.x & 3;
  const int qt = (blockIdx.x >> 2) & 63;
  const int sp = blockIdx.x >> 8;
  const int qrow0 = qt * 64;

  bf16x8 qf[4];
  {
    const bf16_t* qp = q + ((size_t)b * 4096 + qrow0 + w * 16 + lq) * 128 + quad * 8;
#pragma unroll
    for (int ks = 0; ks < 4; ++ks) qf[ks] = *(const bf16x8*)(qp + ks * 32);
  }

  f32x4 accO[8];
#pragma unroll
  for (int i = 0; i < 8; ++i) accO[i] = (f32x4){0.f, 0.f, 0.f, 0.f};
  float mrow[4] = {-1e30f, -1e30f, -1e30f, -1e30f};
  float lrow[4] = {0.f, 0.f, 0.f, 0.f};

  const bf16_t* kbase = kk + (size_t)b * 4096 * 128;
  const bf16_t* vbase = vt + (size_t)b * 4096;
  const float SCL = 0.08838834764831845f * 1.4426950408889634f;
  const int it0 = sp * 32;

  stage_kv(kbase + (size_t)it0 * 64 * 128, vbase + it0 * 64, sK[0], sV[0], tid);
  __syncthreads();

  for (int i = 0; i < 32; ++i) {
    const int buf = i & 1;
    if (i < 31)
      stage_kv(kbase + (size_t)(it0 + i + 1) * 64 * 128, vbase + (it0 + i + 1) * 64,
               sK[buf ^ 1], sV[buf ^ 1], tid);

    f32x4 accS[4];
#pragma unroll
    for (int nt = 0; nt < 4; ++nt) accS[nt] = (f32x4){0.f, 0.f, 0.f, 0.f};
    __builtin_amdgcn_s_setprio(1);
#pragma unroll
    for (int ks = 0; ks < 4; ++ks) {
      const int cc = ks * 4 + quad;
#pragma unroll
      for (int nt = 0; nt < 4; ++nt) {
        int row = nt * 16 + lq;
        bf16x8 kf = *(const bf16x8*)(sK[buf] + row * 128 + ((cc ^ (row & 15)) << 3));
        accS[nt] = MFMA16(qf[ks], kf, accS[nt]);
      }
    }
    __builtin_amdgcn_s_setprio(0);

    float mxs[4];
#pragma unroll
    for (int r = 0; r < 4; ++r) {
      float t0 = fmaxf(fmaxf(accS[0][r], accS[1][r]), fmaxf(accS[2][r], accS[3][r]));
#pragma unroll
      for (int msk = 1; msk < 16; msk <<= 1) t0 = fmaxf(t0, __shfl_xor(t0, msk));
      mxs[r] = t0 * SCL;
    }
    bool grow = (mxs[0] > mrow[0]) || (mxs[1] > mrow[1]) ||
                (mxs[2] > mrow[2]) || (mxs[3] > mrow[3]);
    if (__any(grow)) {
      float al[4];
#pragma unroll
      for (int r = 0; r < 4; ++r) {
        float mn = fmaxf(mrow[r], mxs[r]);
        al[r] = exp2f(mrow[r] - mn);
        mrow[r] = mn;
        lrow[r] *= al[r];
      }
#pragma unroll
      for (int ot = 0; ot < 8; ++ot) {
        accO[ot][0] *= al[0]; accO[ot][1] *= al[1];
        accO[ot][2] *= al[2]; accO[ot][3] *= al[3];
      }
    }
    float ps[4] = {0.f, 0.f, 0.f, 0.f};
#pragma unroll
    for (int nt = 0; nt < 4; ++nt)
#pragma unroll
      for (int r = 0; r < 4; ++r) {
        float p = exp2f(fmaf(accS[nt][r], SCL, -mrow[r]));
        accS[nt][r] = p;
        ps[r] += p;
      }
#pragma unroll
    for (int r = 0; r < 4; ++r) {
      float s = ps[r];
#pragma unroll
      for (int msk = 1; msk < 16; msk <<= 1) s += __shfl_xor(s, msk);
      lrow[r] += s;
    }

#pragma unroll
    for (int nt = 0; nt < 4; ++nt) {
      int key = nt * 16 + lq;
#pragma unroll
      for (int r = 0; r < 4; ++r) {
        int prow = w * 16 + quad * 4 + r;
        sP[prow * 72 + key] = (bf16_t)accS[nt][r];
      }
    }

    __builtin_amdgcn_s_setprio(1);
#pragma unroll
    for (int ks2 = 0; ks2 < 2; ++ks2) {
      const int cc = ks2 * 4 + quad;
      bf16x8 pf = *(const bf16x8*)(sP + (w * 16 + lq) * 72 + cc * 8);
#pragma unroll
      for (int ot = 0; ot < 8; ++ot) {
        int h = ot * 16 + lq;
        bf16x8 vf = *(const bf16x8*)(sV[buf] + h * 64 + ((cc ^ (h & 7)) << 3));
        accO[ot] = MFMA16(pf, vf, accO[ot]);
      }
    }
    __builtin_amdgcn_s_setprio(0);
    __syncthreads();
  }

  float* op = opart + ((size_t)(sp * 4 + b) * 4096 + qrow0 + w * 16) * 128;
#pragma unroll
  for (int ot = 0; ot < 8; ++ot)
#pragma unroll
    for (int r = 0; r < 4; ++r)
      op[(size_t)(quad * 4 + r) * 128 + ot * 16 + lq] = accO[ot][r];
  if (lq == 0) {
#pragma unroll
    for (int r = 0; r < 4; ++r) {
      size_t idx = (size_t)(sp * 4 + b) * 4096 + qrow0 + w * 16 + quad * 4 + r;
      mlm[idx] = mrow[r];
      mll[idx] = lrow[r];
    }
  }
}

// ---------------- merge the 2 key-splits --------------------------------------
__global__ void merge(const float* __restrict__ opart, const float* __restrict__ mlm,
                      const float* __restrict__ mll, float* __restrict__ out) {
  const int idx = blockIdx.x * 256 + threadIdx.x;
  const int h = idx & 127;
  const int row = idx >> 7;
  float m0 = mlm[row], m1 = mlm[16384 + row];
  float l0 = mll[row], l1 = mll[16384 + row];
  float M = fmaxf(m0, m1);
  float w0 = exp2f(m0 - M), w1 = exp2f(m1 - M);
  float L = w0 * l0 + w1 * l1;
  float acc = w0 * opart[(size_t)row * 128 + h] +
              w1 * opart[((size_t)16384 + row) * 128 + h];
  out[idx] = acc / L;
}

extern "C" void kernel_launch(void* const* d_in, const int* in_sizes, int n_in,
                              void* d_out, int out_size, void* d_ws, size_t ws_size,
                              hipStream_t stream) {
  (void)in_sizes; (void)n_in; (void)out_size; (void)ws_size;
  const float* x  = (const float*)d_in[0];
  const float* wq = (const float*)d_in[1];
  const float* wk = (const float*)d_in[2];
  const float* wv = (const float*)d_in[3];

  char* ws = (char*)d_ws;
  bf16_t* wt  = (bf16_t*)ws;                         ws += (size_t)384 * 4096 * 2;
  bf16_t* qb  = (bf16_t*)ws;                         ws += (size_t)16384 * 128 * 2;
  bf16_t* kb  = (bf16_t*)ws;                         ws += (size_t)16384 * 128 * 2;
  bf16_t* vtb = (bf16_t*)ws;                         ws += (size_t)16384 * 128 * 2;
  float*  oqkv = (float*)ws;                         ws += (size_t)2 * 16384 * 384 * 4;
  float*  opart = (float*)ws;                        ws += (size_t)2 * 16384 * 128 * 4;
  float*  mlm = (float*)ws;                          ws += (size_t)2 * 16384 * 4;
  float*  mll = (float*)ws;
  float*  ob  = (float*)d_out;

  dim3 tb(32, 8, 1);
  tr_w<<<dim3(4, 128, 3), tb, 0, stream>>>(wq, wk, wv, wt);
  qkv_ks<<<dim3(256), dim3(512), 0, stream>>>(x, wt, oqkv);
  qkred<<<dim3(4096), dim3(256), 0, stream>>>(oqkv, qb, kb);
  vred<<<dim3(4, 512), tb, 0, stream>>>(oqkv, vtb);
  flash<<<dim3(512), dim3(256), 0, stream>>>(qb, kb, vtb, opart, mlm, mll);
  merge<<<dim3(8192), dim3(256), 0, stream>>>(opart, mlm, mll, ob);
}